// Round 4
// baseline (3586.918 us; speedup 1.0000x reference)
//
#include <hip/hip_runtime.h>
#include <cstdint>
#include <cstddef>

// ---------- types ----------
typedef _Float16 half2v __attribute__((ext_vector_type(2)));
typedef _Float16 half4v __attribute__((ext_vector_type(4)));
typedef _Float16 half8v __attribute__((ext_vector_type(8)));
typedef float f32x4 __attribute__((ext_vector_type(4)));

__device__ __forceinline__ float sigm(float x) { return 1.0f / (1.0f + __expf(-x)); }
__device__ __forceinline__ float tanh_(float x) { return 1.0f - 2.0f / (__expf(2.0f * x) + 1.0f); }

// Problem constants
#define BB 128
#define TT 512
#define II 300
#define IIP 320   // padded K for fp16 path
#define HH 256
#define GG 1024  // 4*H

// ============================================================================
// Kernel 0: convert X (65536x300 f32) and W_ih_f (1024x300 f32) to fp16 with
// zero-padded K=320 rows, enabling 16B-aligned global_load_lds in the GEMM.
// ============================================================================
__global__ __launch_bounds__(256) void cvt_xw(
    const float* __restrict__ X, const float* __restrict__ W,
    _Float16* __restrict__ Xh, _Float16* __restrict__ Wh)
{
    const int total = (65536 + 1024) * 40;   // 8-elem chunks per padded row
    for (int c = blockIdx.x * 256 + threadIdx.x; c < total; c += gridDim.x * 256) {
        const int row = c / 40;
        const int ch = c - row * 40;
        const int k0 = ch * 8;
        const float* src;
        _Float16* dst;
        if (row < 65536) {
            src = X + (size_t)row * II;
            dst = Xh + (size_t)row * IIP;
        } else {
            src = W + (size_t)(row - 65536) * II;
            dst = Wh + (size_t)(row - 65536) * IIP;
        }
        half8v hv;
        if (k0 + 8 <= II) {
            float4 a = *(const float4*)(src + k0);
            float4 b = *(const float4*)(src + k0 + 4);
            hv = half8v{(_Float16)a.x, (_Float16)a.y, (_Float16)a.z, (_Float16)a.w,
                        (_Float16)b.x, (_Float16)b.y, (_Float16)b.z, (_Float16)b.w};
        } else {
#pragma unroll
            for (int q = 0; q < 8; ++q) {
                const int k = k0 + q;
                hv[q] = (k < II) ? (_Float16)src[k] : (_Float16)0.f;
            }
        }
        *(half8v*)(dst + k0) = hv;
    }
}

// ============================================================================
// Kernel 1b: xp GEMM, fp16 inputs via global_load_lds (m97 structure). PROVEN.
// ============================================================================
#if __has_builtin(__builtin_amdgcn_global_load_lds)
#define HAVE_GLL 1
__device__ __forceinline__ void gll16(const _Float16* g, _Float16* l) {
    __builtin_amdgcn_global_load_lds(
        (const __attribute__((address_space(1))) void*)g,
        (__attribute__((address_space(3))) void*)l, 16, 0, 0);
}
#else
#define HAVE_GLL 0
#endif

__global__ __launch_bounds__(256) void gemm_xp_h(
    const _Float16* __restrict__ Xh, const _Float16* __restrict__ Wh,
    const float* __restrict__ bias, _Float16* __restrict__ XP)
{
    __shared__ __align__(16) _Float16 As[128 * 32];
    __shared__ __align__(16) _Float16 Bs[128 * 32];

    const int t = threadIdx.x;
    const int m0 = blockIdx.y * 128;
    const int n0 = blockIdx.x * 128;
    const int lane = t & 63;
    const int wv = t >> 6;
    const int mq = (wv >> 1) * 4;
    const int nq = (wv & 1) * 4;

    int rowd[2], k4d[2], cidx[2];
#pragma unroll
    for (int r = 0; r < 2; ++r) {
        const int c = wv * 128 + r * 64 + lane;
        cidx[r] = c;
        rowd[r] = ((c >> 6) << 4) | (c & 15);
        k4d[r] = (c >> 4) & 3;
    }

    f32x4 acc[4][4];
#pragma unroll
    for (int i = 0; i < 4; ++i)
#pragma unroll
        for (int j = 0; j < 4; ++j) acc[i][j] = f32x4{0.f, 0.f, 0.f, 0.f};

    for (int kc = 0; kc < IIP; kc += 32) {
        __syncthreads();
#pragma unroll
        for (int r = 0; r < 2; ++r) {
            const _Float16* ga = Xh + (size_t)(m0 + rowd[r]) * IIP + kc + k4d[r] * 8;
            const _Float16* gb = Wh + (size_t)(n0 + rowd[r]) * IIP + kc + k4d[r] * 8;
#if HAVE_GLL
            gll16(ga, &As[cidx[r] * 8]);
            gll16(gb, &Bs[cidx[r] * 8]);
#else
            *(half8v*)(&As[cidx[r] * 8]) = *(const half8v*)ga;
            *(half8v*)(&Bs[cidx[r] * 8]) = *(const half8v*)gb;
#endif
        }
        __syncthreads();

        half8v af[4], bf[4];
#pragma unroll
        for (int i = 0; i < 4; ++i) {
            af[i] = *(const half8v*)(&As[(mq + i) * 512 + (lane >> 4) * 128 + (lane & 15) * 8]);
            bf[i] = *(const half8v*)(&Bs[(nq + i) * 512 + (lane >> 4) * 128 + (lane & 15) * 8]);
        }
#pragma unroll
        for (int i = 0; i < 4; ++i)
#pragma unroll
            for (int j = 0; j < 4; ++j)
                acc[i][j] = __builtin_amdgcn_mfma_f32_16x16x32_f16(af[i], bf[j], acc[i][j], 0, 0, 0);
    }

#pragma unroll
    for (int j = 0; j < 4; ++j) {
        const int n = n0 + (nq + j) * 16 + (lane & 15);
        const float bv = bias[n];
#pragma unroll
        for (int i = 0; i < 4; ++i) {
#pragma unroll
            for (int r = 0; r < 4; ++r) {
                const int m = m0 + (mq + i) * 16 + (lane >> 4) * 4 + r;
                XP[(size_t)m * GG + n] = (_Float16)(acc[i][j][r] + bv);
            }
        }
    }
}

// ============================================================================
// Kernel 1 (fallback): xp GEMM from f32 inputs (the proven v1 kernel).
// ============================================================================
__global__ __launch_bounds__(256, 3) void gemm_xp(
    const float* __restrict__ X, const float* __restrict__ W,
    const float* __restrict__ bias, _Float16* __restrict__ XP)
{
    __shared__ _Float16 As[128 * 32];
    __shared__ _Float16 Bs[128 * 32];

    const int t = threadIdx.x;
    const int m0 = blockIdx.y * 128;
    const int n0 = blockIdx.x * 128;
    const int kpos = t & 7;
    const int rbase = t >> 3;
    const int lane = t & 63;
    const int wv = t >> 6;
    const int mq = (wv >> 1) * 4;
    const int nq = (wv & 1) * 4;

    f32x4 acc[4][4];
#pragma unroll
    for (int i = 0; i < 4; ++i)
#pragma unroll
        for (int j = 0; j < 4; ++j) acc[i][j] = f32x4{0.f, 0.f, 0.f, 0.f};

    for (int kc = 0; kc < 320; kc += 32) {
        __syncthreads();
        const int k0 = kc + kpos * 4;
#pragma unroll
        for (int rr = 0; rr < 4; ++rr) {
            const int row = rbase + rr * 32;
            float4 va = {0.f, 0.f, 0.f, 0.f}, vb = {0.f, 0.f, 0.f, 0.f};
            if (k0 < 300) {
                va = *(const float4*)(X + (size_t)(m0 + row) * II + k0);
                vb = *(const float4*)(W + (size_t)(n0 + row) * II + k0);
            }
            const int idx = (row >> 4) * 512 + (kpos >> 1) * 128 + (row & 15) * 8 + (kpos & 1) * 4;
            half4v ha = {(_Float16)va.x, (_Float16)va.y, (_Float16)va.z, (_Float16)va.w};
            half4v hb = {(_Float16)vb.x, (_Float16)vb.y, (_Float16)vb.z, (_Float16)vb.w};
            *(half4v*)(&As[idx]) = ha;
            *(half4v*)(&Bs[idx]) = hb;
        }
        __syncthreads();

        half8v af[4], bf[4];
#pragma unroll
        for (int i = 0; i < 4; ++i) {
            af[i] = *(const half8v*)(&As[(mq + i) * 512 + (lane >> 4) * 128 + (lane & 15) * 8]);
            bf[i] = *(const half8v*)(&Bs[(nq + i) * 512 + (lane >> 4) * 128 + (lane & 15) * 8]);
        }
#pragma unroll
        for (int i = 0; i < 4; ++i)
#pragma unroll
            for (int j = 0; j < 4; ++j)
                acc[i][j] = __builtin_amdgcn_mfma_f32_16x16x32_f16(af[i], bf[j], acc[i][j], 0, 0, 0);
    }

#pragma unroll
    for (int j = 0; j < 4; ++j) {
        const int n = n0 + (nq + j) * 16 + (lane & 15);
        const float bv = bias[n];
#pragma unroll
        for (int i = 0; i < 4; ++i) {
#pragma unroll
            for (int r = 0; r < 4; ++r) {
                const int m = m0 + (mq + i) * 16 + (lane >> 4) * 4 + r;
                XP[(size_t)m * GG + n] = (_Float16)(acc[i][j][r] + bv);
            }
        }
    }
}

// ============================================================================
// Kernel 2 (v4): forward recurrence via MFMA, batch-tiled.
//
// 8 blocks x 16 batch rows; 512 thr (8 waves, waves_per_eu(2,2) -> 256-reg
// unified budget). Per step: G[16][1024] = h[16][256] @ Whh^T (+xp), as
// 512 mfma_f32_16x16x32_f16 (64/wave). Fragment layouts IDENTICAL to the
// proven gemm_xp_h (A: lane holds [m=l&15][k=(l>>4)*8+e]; B: [n=l&15][k=...];
// C: row=(l>>4)*4+r, col=l&15).
//
// Wave w owns cols {g*256 + w*32 + jt*16 + (0..15)} for g=0..3, jt=0..1
// (ct = g*2+jt) => all 4 gate preacts of cell (batch m, j) are in ONE lane:
// acc[jt], acc[2+jt], acc[4+jt], acc[6+jt] at reg r. Cell update lane-local.
//
// Weights: k-slices 0..5 resident as B-frags (48 half8v = 192 regs -> AGPRs,
// MFMA reads them directly); slices 6,7 in 128 KB LDS (gemm Bs layout).
// h ping-pong: 2 x 8 KB in A-frag layout [slice][kq][m][e] with XOR swizzle
// phys = logical ^ (((logical>>7)&3)<<3) on BOTH write and read to spread
// the m-stride-8 write banks. One barrier per step.
// ============================================================================
__global__ __attribute__((amdgpu_flat_work_group_size(512, 512), amdgpu_waves_per_eu(2, 2)))
void lstm_fwd(
    const float* __restrict__ Whh, const _Float16* __restrict__ XP,
    float* __restrict__ HF)
{
    __shared__ __align__(16) _Float16 wlds[65536];   // 128 KB: [s][ntile][kq][n16][8]
    __shared__ __align__(16) _Float16 hl[2][4096];   // 2 x 8 KB: [slice][kq][m][8]

    const int t = threadIdx.x;
    const int b0 = blockIdx.x * 16;
    const int l = t & 63;
    const int w = t >> 6;            // wave 0..7
    const int n16 = l & 15;
    const int kq = l >> 4;           // 0..3

    // ---- resident B-fragments: slices ks=0..5 for 8 col-tiles (192 regs) ----
    half8v wr[8][6];
#pragma unroll
    for (int ct = 0; ct < 8; ++ct) {
        const int nct = (ct >> 1) * 256 + w * 32 + (ct & 1) * 16;
        const float* wp = Whh + (size_t)(nct + n16) * HH + kq * 8;
#pragma unroll
        for (int ks = 0; ks < 6; ++ks) {
            float4 a = *(const float4*)(wp + ks * 32);
            float4 b = *(const float4*)(wp + ks * 32 + 4);
            wr[ct][ks] = half8v{(_Float16)a.x, (_Float16)a.y, (_Float16)a.z, (_Float16)a.w,
                                (_Float16)b.x, (_Float16)b.y, (_Float16)b.z, (_Float16)b.w};
        }
    }
    // ---- LDS B-fragments: slices 6,7 (each thread fills 16 frag-slots) ----
#pragma unroll
    for (int i = 0; i < 16; ++i) {
        const int idx = i * 512 + t;          // 0..8191
        const int sn16 = idx & 15;
        const int skq = (idx >> 4) & 3;
        const int snt = (idx >> 6) & 63;
        const int ss  = (idx >> 12) & 1;
        const float* sp = Whh + (size_t)(snt * 16 + sn16) * HH + (6 + ss) * 32 + skq * 8;
        float4 a = *(const float4*)sp;
        float4 b = *(const float4*)(sp + 4);
        *(half8v*)(&wlds[idx * 8]) = half8v{(_Float16)a.x, (_Float16)a.y, (_Float16)a.z, (_Float16)a.w,
                                            (_Float16)b.x, (_Float16)b.y, (_Float16)b.z, (_Float16)b.w};
    }
    // ---- zero h(t=-1) ----
#pragma unroll
    for (int i = 0; i < 8; ++i) hl[0][i * 512 + t] = (_Float16)0.f;

    float cst[8];
#pragma unroll
    for (int i = 0; i < 8; ++i) cst[i] = 0.f;
    __syncthreads();

    for (int ts = 0; ts < TT; ++ts) {
        const int cur = ts & 1;
        const _Float16* hr = &hl[cur][0];

        f32x4 acc[8];
#pragma unroll
        for (int ct = 0; ct < 8; ++ct) acc[ct] = f32x4{0.f, 0.f, 0.f, 0.f};

        // slices 0..5: B from registers
#pragma unroll
        for (int ks = 0; ks < 6; ++ks) {
            const int ra = (ks * 512 + kq * 128 + n16 * 8) ^ (kq << 3);
            half8v A = *(const half8v*)(&hr[ra]);
#pragma unroll
            for (int ct = 0; ct < 8; ++ct)
                acc[ct] = __builtin_amdgcn_mfma_f32_16x16x32_f16(A, wr[ct][ks], acc[ct], 0, 0, 0);
        }
        // slices 6,7: B from LDS
#pragma unroll
        for (int s = 0; s < 2; ++s) {
            const int ks = 6 + s;
            const int ra = (ks * 512 + kq * 128 + n16 * 8) ^ (kq << 3);
            half8v A = *(const half8v*)(&hr[ra]);
#pragma unroll
            for (int ct = 0; ct < 8; ++ct) {
                const int nt = (ct >> 1) * 16 + w * 2 + (ct & 1);
                half8v Bv = *(const half8v*)(&wlds[(((s * 64 + nt) * 4 + kq) * 16 + n16) * 8]);
                acc[ct] = __builtin_amdgcn_mfma_f32_16x16x32_f16(A, Bv, acc[ct], 0, 0, 0);
            }
        }

        // tail: two jt-passes, each loads 16 xp scalars then updates 4 cells
        _Float16* hw = &hl[cur ^ 1][0];
#pragma unroll
        for (int jt = 0; jt < 2; ++jt) {
            _Float16 xv[16];
#pragma unroll
            for (int r = 0; r < 4; ++r) {
                const _Float16* xrow = XP + (((size_t)(b0 + kq * 4 + r) * TT) + ts) * GG
                                          + w * 32 + jt * 16 + n16;
#pragma unroll
                for (int g = 0; g < 4; ++g) xv[r * 4 + g] = xrow[g * 256];
            }
#pragma unroll
            for (int r = 0; r < 4; ++r) {
                const int m = kq * 4 + r;
                const float gi = acc[0 + jt][r] + (float)xv[r * 4 + 0];
                const float gf = acc[2 + jt][r] + (float)xv[r * 4 + 1];
                const float gg = acc[4 + jt][r] + (float)xv[r * 4 + 2];
                const float go = acc[6 + jt][r] + (float)xv[r * 4 + 3];
                float cc = cst[jt * 4 + r];
                cc = sigm(gf) * cc + sigm(gi) * tanh_(gg);
                cst[jt * 4 + r] = cc;
                const float h = sigm(go) * tanh_(cc);
                const int q = (jt * 16 + n16) >> 3;
                const int logi = w * 512 + q * 128 + m * 8 + (n16 & 7);
                hw[logi ^ (q << 3)] = (_Float16)h;
                if (ts == TT - 1) HF[(size_t)(b0 + m) * HH + (w * 32 + jt * 16 + n16)] = h;
            }
        }
        __syncthreads();
    }
}

// ============================================================================
// Kernel 3: backward direction = ONE cell step on x[:, T-1] with h0=c0=0.
// ============================================================================
__global__ __launch_bounds__(256) void lstm_bwd(
    const float* __restrict__ X, const float* __restrict__ Wih,
    const float* __restrict__ bb, float* __restrict__ HB)
{
    __shared__ float xs[II];
    const int b = blockIdx.x, t = threadIdx.x;
    const float* xrow = X + ((size_t)b * TT + (TT - 1)) * II;
    if (t < 75) *(float4*)(&xs[t * 4]) = *(const float4*)(xrow + t * 4);
    __syncthreads();
    if (t < HH) {
        float ai = 0.f, ag = 0.f, ao = 0.f;
        const float4* wi = (const float4*)(Wih + (size_t)t * II);
        const float4* wg = (const float4*)(Wih + (size_t)(t + 512) * II);
        const float4* wo = (const float4*)(Wih + (size_t)(t + 768) * II);
        for (int k4 = 0; k4 < 75; ++k4) {
            float4 xv = *(const float4*)(&xs[k4 * 4]);
            float4 a = wi[k4], g4 = wg[k4], o4 = wo[k4];
            ai += xv.x * a.x + xv.y * a.y + xv.z * a.z + xv.w * a.w;
            ag += xv.x * g4.x + xv.y * g4.y + xv.z * g4.z + xv.w * g4.w;
            ao += xv.x * o4.x + xv.y * o4.y + xv.z * o4.z + xv.w * o4.w;
        }
        ai += bb[t];
        ag += bb[t + 512];
        ao += bb[t + 768];
        const float cg = sigm(ai) * tanh_(ag);
        HB[(size_t)b * HH + t] = sigm(ao) * tanh_(cg);
    }
}

// ============================================================================
// Kernel 4: out[b][jj] = [hf|hb] . W_lin[jj] + b_lin[jj]
// ============================================================================
__global__ __launch_bounds__(256) void final_k(
    const float* __restrict__ HF, const float* __restrict__ HB,
    const float* __restrict__ Wlin, const float* __restrict__ blin,
    float* __restrict__ OUT)
{
    const int t = threadIdx.x;
    const int b = t >> 1, jj = t & 1;
    float acc = blin[jj];
    const float* wf = Wlin + jj * 512;
    const float* wb = Wlin + jj * 512 + 256;
    const float* hf = HF + (size_t)b * HH;
    const float* hb = HB + (size_t)b * HH;
    for (int k = 0; k < HH; k += 4) {
        float4 h4 = *(const float4*)(hf + k);
        float4 w4 = *(const float4*)(wf + k);
        float4 g4 = *(const float4*)(hb + k);
        float4 v4 = *(const float4*)(wb + k);
        acc += h4.x * w4.x + h4.y * w4.y + h4.z * w4.z + h4.w * w4.w;
        acc += g4.x * v4.x + g4.y * v4.y + g4.z * v4.z + g4.w * v4.w;
    }
    OUT[b * 2 + jj] = acc;
}

// ============================================================================
extern "C" void kernel_launch(void* const* d_in, const int* in_sizes, int n_in,
                              void* d_out, int out_size, void* d_ws, size_t ws_size,
                              hipStream_t stream)
{
    const float* x = (const float*)d_in[0];
    const float* Wihf = (const float*)d_in[1];
    const float* Whhf = (const float*)d_in[2];
    const float* bf = (const float*)d_in[3];
    const float* Wihb = (const float*)d_in[4];
    const float* Whhb = (const float*)d_in[5];
    const float* bbv = (const float*)d_in[6];
    const float* Wlin = (const float*)d_in[7];
    const float* blin = (const float*)d_in[8];
    float* out = (float*)d_out;
    (void)Whhb; (void)in_sizes; (void)n_in; (void)out_size;

    // workspace layout: xp fp16 | hf f32 | hb f32 | Xh fp16 | Wh fp16
    const size_t XP_B = (size_t)BB * TT * GG * 2;            // 134,217,728
    const size_t H_B  = (size_t)BB * HH * 4;                 // 131,072
    const size_t XH_B = (size_t)65536 * IIP * 2;             // 41,943,040
    const size_t WH_B = (size_t)GG * IIP * 2;                // 655,360

    _Float16* xp = (_Float16*)d_ws;
    float* hf = (float*)((char*)d_ws + XP_B);
    float* hb = hf + (size_t)BB * HH;
    _Float16* Xh = (_Float16*)((char*)d_ws + XP_B + 2 * H_B);
    _Float16* Wh = Xh + (size_t)65536 * IIP;

    lstm_bwd<<<BB, 256, 0, stream>>>(x, Wihb, bbv, hb);
    if (ws_size >= XP_B + 2 * H_B + XH_B + WH_B) {
        cvt_xw<<<2048, 256, 0, stream>>>(x, Wihf, Xh, Wh);
        gemm_xp_h<<<dim3(GG / 128, (BB * TT) / 128), 256, 0, stream>>>(Xh, Wh, bf, xp);
    } else {
        gemm_xp<<<dim3(GG / 128, (BB * TT) / 128), 256, 0, stream>>>(x, Wihf, bf, xp);
    }
    lstm_fwd<<<8, 512, 0, stream>>>(Whhf, xp, hf);
    final_k<<<1, 256, 0, stream>>>(hf, hb, Wlin, blin, out);
}

// Round 5
// 1292.398 us; speedup vs baseline: 2.7754x; 2.7754x over previous
//
#include <hip/hip_runtime.h>
#include <cstdint>
#include <cstddef>

// ---------- types ----------
typedef _Float16 half2v __attribute__((ext_vector_type(2)));
typedef _Float16 half4v __attribute__((ext_vector_type(4)));
typedef _Float16 half8v __attribute__((ext_vector_type(8)));
typedef float f32x4 __attribute__((ext_vector_type(4)));
typedef int int4v __attribute__((ext_vector_type(4)));

#if __has_builtin(__builtin_amdgcn_fdot2)
#define FDOT2(a, b, c) __builtin_amdgcn_fdot2((a), (b), (c), false)
#else
static __device__ __forceinline__ float fdot2_fb(half2v a, half2v b, float c) {
    return c + (float)a[0] * (float)b[0] + (float)a[1] * (float)b[1];
}
#define FDOT2(a, b, c) fdot2_fb((a), (b), (c))
#endif

#define SV2(v, i0, i1) __builtin_shufflevector((v), (v), (i0), (i1))

// lane-pair (l ^ 1) 16-byte exchange on the VALU pipe (DPP quad_perm),
// NOT the LDS pipe (ds_swizzle/bpermute would defeat the purpose).
#if __has_builtin(__builtin_amdgcn_mov_dpp)
static __device__ __forceinline__ half8v dpp_xor1(half8v v) {
    int4v iv = __builtin_bit_cast(int4v, v);
    int4v ov;
    // quad_perm [1,0,3,2] = 0xB1 -> lane ^= 1
    ov[0] = __builtin_amdgcn_mov_dpp(iv[0], 0xB1, 0xF, 0xF, true);
    ov[1] = __builtin_amdgcn_mov_dpp(iv[1], 0xB1, 0xF, 0xF, true);
    ov[2] = __builtin_amdgcn_mov_dpp(iv[2], 0xB1, 0xF, 0xF, true);
    ov[3] = __builtin_amdgcn_mov_dpp(iv[3], 0xB1, 0xF, 0xF, true);
    return __builtin_bit_cast(half8v, ov);
}
#else
static __device__ __forceinline__ half8v dpp_xor1(half8v v) {
    int4v iv = __builtin_bit_cast(int4v, v);
    int4v ov;
    ov[0] = __shfl_xor(iv[0], 1, 64);
    ov[1] = __shfl_xor(iv[1], 1, 64);
    ov[2] = __shfl_xor(iv[2], 1, 64);
    ov[3] = __shfl_xor(iv[3], 1, 64);
    return __builtin_bit_cast(half8v, ov);
}
#endif

__device__ __forceinline__ float sigm(float x) { return 1.0f / (1.0f + __expf(-x)); }
__device__ __forceinline__ float tanh_(float x) { return 1.0f - 2.0f / (__expf(2.0f * x) + 1.0f); }

// Problem constants
#define BB 128
#define TT 512
#define II 300
#define IIP 320   // padded K for fp16 path
#define HH 256
#define GG 1024  // 4*H

// ============================================================================
// Kernel 0: convert X (65536x300 f32) and W_ih_f (1024x300 f32) to fp16 with
// zero-padded K=320 rows, enabling 16B-aligned global_load_lds in the GEMM.
// ============================================================================
__global__ __launch_bounds__(256) void cvt_xw(
    const float* __restrict__ X, const float* __restrict__ W,
    _Float16* __restrict__ Xh, _Float16* __restrict__ Wh)
{
    const int total = (65536 + 1024) * 40;   // 8-elem chunks per padded row
    for (int c = blockIdx.x * 256 + threadIdx.x; c < total; c += gridDim.x * 256) {
        const int row = c / 40;
        const int ch = c - row * 40;
        const int k0 = ch * 8;
        const float* src;
        _Float16* dst;
        if (row < 65536) {
            src = X + (size_t)row * II;
            dst = Xh + (size_t)row * IIP;
        } else {
            src = W + (size_t)(row - 65536) * II;
            dst = Wh + (size_t)(row - 65536) * IIP;
        }
        half8v hv;
        if (k0 + 8 <= II) {
            float4 a = *(const float4*)(src + k0);
            float4 b = *(const float4*)(src + k0 + 4);
            hv = half8v{(_Float16)a.x, (_Float16)a.y, (_Float16)a.z, (_Float16)a.w,
                        (_Float16)b.x, (_Float16)b.y, (_Float16)b.z, (_Float16)b.w};
        } else {
#pragma unroll
            for (int q = 0; q < 8; ++q) {
                const int k = k0 + q;
                hv[q] = (k < II) ? (_Float16)src[k] : (_Float16)0.f;
            }
        }
        *(half8v*)(dst + k0) = hv;
    }
}

// ============================================================================
// Kernel 1b: xp GEMM, fp16 inputs via global_load_lds (m97 structure). PROVEN.
// ============================================================================
#if __has_builtin(__builtin_amdgcn_global_load_lds)
#define HAVE_GLL 1
__device__ __forceinline__ void gll16(const _Float16* g, _Float16* l) {
    __builtin_amdgcn_global_load_lds(
        (const __attribute__((address_space(1))) void*)g,
        (__attribute__((address_space(3))) void*)l, 16, 0, 0);
}
#else
#define HAVE_GLL 0
#endif

__global__ __launch_bounds__(256) void gemm_xp_h(
    const _Float16* __restrict__ Xh, const _Float16* __restrict__ Wh,
    const float* __restrict__ bias, _Float16* __restrict__ XP)
{
    __shared__ __align__(16) _Float16 As[128 * 32];
    __shared__ __align__(16) _Float16 Bs[128 * 32];

    const int t = threadIdx.x;
    const int m0 = blockIdx.y * 128;
    const int n0 = blockIdx.x * 128;
    const int lane = t & 63;
    const int wv = t >> 6;
    const int mq = (wv >> 1) * 4;
    const int nq = (wv & 1) * 4;

    int rowd[2], k4d[2], cidx[2];
#pragma unroll
    for (int r = 0; r < 2; ++r) {
        const int c = wv * 128 + r * 64 + lane;
        cidx[r] = c;
        rowd[r] = ((c >> 6) << 4) | (c & 15);
        k4d[r] = (c >> 4) & 3;
    }

    f32x4 acc[4][4];
#pragma unroll
    for (int i = 0; i < 4; ++i)
#pragma unroll
        for (int j = 0; j < 4; ++j) acc[i][j] = f32x4{0.f, 0.f, 0.f, 0.f};

    for (int kc = 0; kc < IIP; kc += 32) {
        __syncthreads();
#pragma unroll
        for (int r = 0; r < 2; ++r) {
            const _Float16* ga = Xh + (size_t)(m0 + rowd[r]) * IIP + kc + k4d[r] * 8;
            const _Float16* gb = Wh + (size_t)(n0 + rowd[r]) * IIP + kc + k4d[r] * 8;
#if HAVE_GLL
            gll16(ga, &As[cidx[r] * 8]);
            gll16(gb, &Bs[cidx[r] * 8]);
#else
            *(half8v*)(&As[cidx[r] * 8]) = *(const half8v*)ga;
            *(half8v*)(&Bs[cidx[r] * 8]) = *(const half8v*)gb;
#endif
        }
        __syncthreads();

        half8v af[4], bf[4];
#pragma unroll
        for (int i = 0; i < 4; ++i) {
            af[i] = *(const half8v*)(&As[(mq + i) * 512 + (lane >> 4) * 128 + (lane & 15) * 8]);
            bf[i] = *(const half8v*)(&Bs[(nq + i) * 512 + (lane >> 4) * 128 + (lane & 15) * 8]);
        }
#pragma unroll
        for (int i = 0; i < 4; ++i)
#pragma unroll
            for (int j = 0; j < 4; ++j)
                acc[i][j] = __builtin_amdgcn_mfma_f32_16x16x32_f16(af[i], bf[j], acc[i][j], 0, 0, 0);
    }

#pragma unroll
    for (int j = 0; j < 4; ++j) {
        const int n = n0 + (nq + j) * 16 + (lane & 15);
        const float bv = bias[n];
#pragma unroll
        for (int i = 0; i < 4; ++i) {
#pragma unroll
            for (int r = 0; r < 4; ++r) {
                const int m = m0 + (mq + i) * 16 + (lane >> 4) * 4 + r;
                XP[(size_t)m * GG + n] = (_Float16)(acc[i][j][r] + bv);
            }
        }
    }
}

// ============================================================================
// Kernel 1 (fallback): xp GEMM from f32 inputs (the proven v1 kernel).
// ============================================================================
__global__ __launch_bounds__(256, 3) void gemm_xp(
    const float* __restrict__ X, const float* __restrict__ W,
    const float* __restrict__ bias, _Float16* __restrict__ XP)
{
    __shared__ _Float16 As[128 * 32];
    __shared__ _Float16 Bs[128 * 32];

    const int t = threadIdx.x;
    const int m0 = blockIdx.y * 128;
    const int n0 = blockIdx.x * 128;
    const int kpos = t & 7;
    const int rbase = t >> 3;
    const int lane = t & 63;
    const int wv = t >> 6;
    const int mq = (wv >> 1) * 4;
    const int nq = (wv & 1) * 4;

    f32x4 acc[4][4];
#pragma unroll
    for (int i = 0; i < 4; ++i)
#pragma unroll
        for (int j = 0; j < 4; ++j) acc[i][j] = f32x4{0.f, 0.f, 0.f, 0.f};

    for (int kc = 0; kc < 320; kc += 32) {
        __syncthreads();
        const int k0 = kc + kpos * 4;
#pragma unroll
        for (int rr = 0; rr < 4; ++rr) {
            const int row = rbase + rr * 32;
            float4 va = {0.f, 0.f, 0.f, 0.f}, vb = {0.f, 0.f, 0.f, 0.f};
            if (k0 < 300) {
                va = *(const float4*)(X + (size_t)(m0 + row) * II + k0);
                vb = *(const float4*)(W + (size_t)(n0 + row) * II + k0);
            }
            const int idx = (row >> 4) * 512 + (kpos >> 1) * 128 + (row & 15) * 8 + (kpos & 1) * 4;
            half4v ha = {(_Float16)va.x, (_Float16)va.y, (_Float16)va.z, (_Float16)va.w};
            half4v hb = {(_Float16)vb.x, (_Float16)vb.y, (_Float16)vb.z, (_Float16)vb.w};
            *(half4v*)(&As[idx]) = ha;
            *(half4v*)(&Bs[idx]) = hb;
        }
        __syncthreads();

        half8v af[4], bf[4];
#pragma unroll
        for (int i = 0; i < 4; ++i) {
            af[i] = *(const half8v*)(&As[(mq + i) * 512 + (lane >> 4) * 128 + (lane & 15) * 8]);
            bf[i] = *(const half8v*)(&Bs[(nq + i) * 512 + (lane >> 4) * 128 + (lane & 15) * 8]);
        }
#pragma unroll
        for (int i = 0; i < 4; ++i)
#pragma unroll
            for (int j = 0; j < 4; ++j)
                acc[i][j] = __builtin_amdgcn_mfma_f32_16x16x32_f16(af[i], bf[j], acc[i][j], 0, 0, 0);
    }

#pragma unroll
    for (int j = 0; j < 4; ++j) {
        const int n = n0 + (nq + j) * 16 + (lane & 15);
        const float bv = bias[n];
#pragma unroll
        for (int i = 0; i < 4; ++i) {
#pragma unroll
            for (int r = 0; r < 4; ++r) {
                const int m = m0 + (mq + i) * 16 + (lane >> 4) * 4 + r;
                XP[(size_t)m * GG + n] = (_Float16)(acc[i][j][r] + bv);
            }
        }
    }
}

// ============================================================================
// Kernel 2 (v5): v1 structure + lane-pair h-chunk sharing over DPP.
//
// v1 was LDS-instr-bound: 48 ds_read_b128/thread/step x 8 waves x ~12 cyc
// ~= the measured 4617 cyc/step. v5 halves the h-read count (32 -> 16):
// lanes l and l^1 each read alternate 16B h-chunks; the partner's chunk
// arrives via v_mov_dpp quad_perm (VALU pipe, 4 dwords). ZERO selects:
// odd lanes store their VGPR weight copies in chunk-swapped order at init,
// so 'mine' always multiplies w[slot even], 'partner' w[slot odd].
// Everything else (mapping, pair-exchange via shfl_xor(32), 1 barrier/step,
// 192 resident ks + 64 LDS ks) is v1 verbatim.
// ============================================================================
__global__ __attribute__((amdgpu_flat_work_group_size(512, 512), amdgpu_waves_per_eu(2, 2)))
void lstm_fwd(
    const float* __restrict__ Whh, const _Float16* __restrict__ XP,
    float* __restrict__ HF)
{
    __shared__ _Float16 wlds[8 * GG * 8];            // 128 KB: [grp][row][8]
    __shared__ __align__(16) _Float16 hlds[2][HH];   // 1 KB ping-pong

    const int t = threadIdx.x;
    const int b = blockIdx.x;
    const int l = t & 63;
    const int wv = t >> 6;
    const int par = l & 1;                 // lane pair parity
    const int half = l >> 5;               // 0: (i,g) rows, 1: (f,o) rows
    const int j = wv * 32 + (l & 31);      // gate index 0..255
    const int row0 = j + (half ? 256 : 0); // i_j or f_j
    const int row1 = row0 + 512;           // g_j or o_j

    // ---- resident weights: k = 0..191, chunk order swapped on odd lanes ----
    // slot chunk c holds source chunk (c ^ par); 'mine' (h chunk 2cp+par)
    // then matches slots [cp*8..+3], 'partner' matches [cp*8+4..+7].
    half2v w0[96], w1[96];
#pragma unroll
    for (int i = 0; i < 48; ++i) {
        const int c = i >> 1, p = i & 1;
        const int cs = c ^ par;
        float4 v = *(const float4*)(Whh + (size_t)row0 * HH + cs * 8 + p * 4);
        w0[2 * i]     = half2v{(_Float16)v.x, (_Float16)v.y};
        w0[2 * i + 1] = half2v{(_Float16)v.z, (_Float16)v.w};
    }
#pragma unroll
    for (int i = 0; i < 48; ++i) {
        const int c = i >> 1, p = i & 1;
        const int cs = c ^ par;
        float4 v = *(const float4*)(Whh + (size_t)row1 * HH + cs * 8 + p * 4);
        w1[2 * i]     = half2v{(_Float16)v.x, (_Float16)v.y};
        w1[2 * i + 1] = half2v{(_Float16)v.z, (_Float16)v.w};
    }
    // ---- LDS weights: k = 192..255, filled by row index t and t+512 ----
#pragma unroll
    for (int grp = 0; grp < 8; ++grp) {
        float4 a  = *(const float4*)(Whh + (size_t)t * HH + 192 + grp * 8);
        float4 c4 = *(const float4*)(Whh + (size_t)t * HH + 192 + grp * 8 + 4);
        half8v hv = {(_Float16)a.x, (_Float16)a.y, (_Float16)a.z, (_Float16)a.w,
                     (_Float16)c4.x, (_Float16)c4.y, (_Float16)c4.z, (_Float16)c4.w};
        *(half8v*)(&wlds[grp * (GG * 8) + t * 8]) = hv;
        float4 a2 = *(const float4*)(Whh + (size_t)(t + 512) * HH + 192 + grp * 8);
        float4 c2 = *(const float4*)(Whh + (size_t)(t + 512) * HH + 192 + grp * 8 + 4);
        half8v hv2 = {(_Float16)a2.x, (_Float16)a2.y, (_Float16)a2.z, (_Float16)a2.w,
                      (_Float16)c2.x, (_Float16)c2.y, (_Float16)c2.z, (_Float16)c2.w};
        *(half8v*)(&wlds[grp * (GG * 8) + (t + 512) * 8]) = hv2;
    }
    if (t < HH) hlds[0][t] = (_Float16)0.f;
    float c = 0.0f;
    __syncthreads();

    const _Float16* xp_b = XP + (size_t)b * TT * GG;
    _Float16 x0 = xp_b[row0];
    _Float16 x1 = xp_b[row1];

    for (int ts = 0; ts < TT; ++ts) {
        const int p = ts & 1;
        const _Float16* hrd = &hlds[p][0];
        // prefetch next step's xp (full step of latency to land)
        const _Float16* xp_n = xp_b + ((ts < TT - 1) ? GG : 0);
        const _Float16 nx0 = xp_n[row0];
        const _Float16 nx1 = xp_n[row1];

        float a0 = 0.f, a1 = 0.f;
#pragma unroll
        for (int cp = 0; cp < 12; ++cp) {  // k = 0..191: 12 chunk-pairs
            half8v mine = *(const half8v*)(&hrd[(cp * 2 + par) * 8]);
            half8v oth  = dpp_xor1(mine);
            a0 = FDOT2(SV2(mine, 0, 1), w0[cp * 8 + 0], a0);
            a1 = FDOT2(SV2(mine, 0, 1), w1[cp * 8 + 0], a1);
            a0 = FDOT2(SV2(mine, 2, 3), w0[cp * 8 + 1], a0);
            a1 = FDOT2(SV2(mine, 2, 3), w1[cp * 8 + 1], a1);
            a0 = FDOT2(SV2(mine, 4, 5), w0[cp * 8 + 2], a0);
            a1 = FDOT2(SV2(mine, 4, 5), w1[cp * 8 + 2], a1);
            a0 = FDOT2(SV2(mine, 6, 7), w0[cp * 8 + 3], a0);
            a1 = FDOT2(SV2(mine, 6, 7), w1[cp * 8 + 3], a1);
            a0 = FDOT2(SV2(oth, 0, 1),  w0[cp * 8 + 4], a0);
            a1 = FDOT2(SV2(oth, 0, 1),  w1[cp * 8 + 4], a1);
            a0 = FDOT2(SV2(oth, 2, 3),  w0[cp * 8 + 5], a0);
            a1 = FDOT2(SV2(oth, 2, 3),  w1[cp * 8 + 5], a1);
            a0 = FDOT2(SV2(oth, 4, 5),  w0[cp * 8 + 6], a0);
            a1 = FDOT2(SV2(oth, 4, 5),  w1[cp * 8 + 6], a1);
            a0 = FDOT2(SV2(oth, 6, 7),  w0[cp * 8 + 7], a0);
            a1 = FDOT2(SV2(oth, 6, 7),  w1[cp * 8 + 7], a1);
        }
#pragma unroll
        for (int gp = 0; gp < 4; ++gp) {   // k = 192..255: 4 grp-pairs
            const int myg = gp * 2 + par;
            const int og  = gp * 2 + (1 - par);
            half8v mine = *(const half8v*)(&hrd[192 + myg * 8]);
            half8v oth  = dpp_xor1(mine);
            {
                half8v wa = *(const half8v*)(&wlds[myg * (GG * 8) + row0 * 8]);
                half8v wb = *(const half8v*)(&wlds[myg * (GG * 8) + row1 * 8]);
                a0 = FDOT2(SV2(mine, 0, 1), SV2(wa, 0, 1), a0);
                a1 = FDOT2(SV2(mine, 0, 1), SV2(wb, 0, 1), a1);
                a0 = FDOT2(SV2(mine, 2, 3), SV2(wa, 2, 3), a0);
                a1 = FDOT2(SV2(mine, 2, 3), SV2(wb, 2, 3), a1);
                a0 = FDOT2(SV2(mine, 4, 5), SV2(wa, 4, 5), a0);
                a1 = FDOT2(SV2(mine, 4, 5), SV2(wb, 4, 5), a1);
                a0 = FDOT2(SV2(mine, 6, 7), SV2(wa, 6, 7), a0);
                a1 = FDOT2(SV2(mine, 6, 7), SV2(wb, 6, 7), a1);
            }
            {
                half8v wa = *(const half8v*)(&wlds[og * (GG * 8) + row0 * 8]);
                half8v wb = *(const half8v*)(&wlds[og * (GG * 8) + row1 * 8]);
                a0 = FDOT2(SV2(oth, 0, 1), SV2(wa, 0, 1), a0);
                a1 = FDOT2(SV2(oth, 0, 1), SV2(wb, 0, 1), a1);
                a0 = FDOT2(SV2(oth, 2, 3), SV2(wa, 2, 3), a0);
                a1 = FDOT2(SV2(oth, 2, 3), SV2(wb, 2, 3), a1);
                a0 = FDOT2(SV2(oth, 4, 5), SV2(wa, 4, 5), a0);
                a1 = FDOT2(SV2(oth, 4, 5), SV2(wb, 4, 5), a1);
                a0 = FDOT2(SV2(oth, 6, 7), SV2(wa, 6, 7), a0);
                a1 = FDOT2(SV2(oth, 6, 7), SV2(wb, 6, 7), a1);
            }
        }
        const float o0 = a0 + (float)x0;
        const float o1 = a1 + (float)x1;
        // partner exchange within the wave (lanes l <-> l^32)
        const float p0 = __shfl_xor(o0, 32, 64);
        const float p1 = __shfl_xor(o1, 32, 64);
        const float gi = half ? p0 : o0;
        const float gg = half ? p1 : o1;
        const float gf = half ? o0 : p0;
        const float go = half ? o1 : p1;
        c = sigm(gf) * c + sigm(gi) * tanh_(gg);
        const float h = sigm(go) * tanh_(c);
        if (!half) {
            hlds[p ^ 1][j] = (_Float16)h;
            if (ts == TT - 1) HF[(size_t)b * HH + j] = h;
        }
        __syncthreads();

        x0 = nx0;
        x1 = nx1;
        xp_b = xp_n;
    }
}

// ============================================================================
// Kernel 3: backward direction = ONE cell step on x[:, T-1] with h0=c0=0.
// ============================================================================
__global__ __launch_bounds__(256) void lstm_bwd(
    const float* __restrict__ X, const float* __restrict__ Wih,
    const float* __restrict__ bb, float* __restrict__ HB)
{
    __shared__ float xs[II];
    const int b = blockIdx.x, t = threadIdx.x;
    const float* xrow = X + ((size_t)b * TT + (TT - 1)) * II;
    if (t < 75) *(float4*)(&xs[t * 4]) = *(const float4*)(xrow + t * 4);
    __syncthreads();
    if (t < HH) {
        float ai = 0.f, ag = 0.f, ao = 0.f;
        const float4* wi = (const float4*)(Wih + (size_t)t * II);
        const float4* wg = (const float4*)(Wih + (size_t)(t + 512) * II);
        const float4* wo = (const float4*)(Wih + (size_t)(t + 768) * II);
        for (int k4 = 0; k4 < 75; ++k4) {
            float4 xv = *(const float4*)(&xs[k4 * 4]);
            float4 a = wi[k4], g4 = wg[k4], o4 = wo[k4];
            ai += xv.x * a.x + xv.y * a.y + xv.z * a.z + xv.w * a.w;
            ag += xv.x * g4.x + xv.y * g4.y + xv.z * g4.z + xv.w * g4.w;
            ao += xv.x * o4.x + xv.y * o4.y + xv.z * o4.z + xv.w * o4.w;
        }
        ai += bb[t];
        ag += bb[t + 512];
        ao += bb[t + 768];
        const float cg = sigm(ai) * tanh_(ag);
        HB[(size_t)b * HH + t] = sigm(ao) * tanh_(cg);
    }
}

// ============================================================================
// Kernel 4: out[b][jj] = [hf|hb] . W_lin[jj] + b_lin[jj]
// ============================================================================
__global__ __launch_bounds__(256) void final_k(
    const float* __restrict__ HF, const float* __restrict__ HB,
    const float* __restrict__ Wlin, const float* __restrict__ blin,
    float* __restrict__ OUT)
{
    const int t = threadIdx.x;
    const int b = t >> 1, jj = t & 1;
    float acc = blin[jj];
    const float* wf = Wlin + jj * 512;
    const float* wb = Wlin + jj * 512 + 256;
    const float* hf = HF + (size_t)b * HH;
    const float* hb = HB + (size_t)b * HH;
    for (int k = 0; k < HH; k += 4) {
        float4 h4 = *(const float4*)(hf + k);
        float4 w4 = *(const float4*)(wf + k);
        float4 g4 = *(const float4*)(hb + k);
        float4 v4 = *(const float4*)(wb + k);
        acc += h4.x * w4.x + h4.y * w4.y + h4.z * w4.z + h4.w * w4.w;
        acc += g4.x * v4.x + g4.y * v4.y + g4.z * v4.z + g4.w * v4.w;
    }
    OUT[b * 2 + jj] = acc;
}

// ============================================================================
extern "C" void kernel_launch(void* const* d_in, const int* in_sizes, int n_in,
                              void* d_out, int out_size, void* d_ws, size_t ws_size,
                              hipStream_t stream)
{
    const float* x = (const float*)d_in[0];
    const float* Wihf = (const float*)d_in[1];
    const float* Whhf = (const float*)d_in[2];
    const float* bf = (const float*)d_in[3];
    const float* Wihb = (const float*)d_in[4];
    const float* Whhb = (const float*)d_in[5];
    const float* bbv = (const float*)d_in[6];
    const float* Wlin = (const float*)d_in[7];
    const float* blin = (const float*)d_in[8];
    float* out = (float*)d_out;
    (void)Whhb; (void)in_sizes; (void)n_in; (void)out_size;

    // workspace layout: xp fp16 | hf f32 | hb f32 | Xh fp16 | Wh fp16
    const size_t XP_B = (size_t)BB * TT * GG * 2;            // 134,217,728
    const size_t H_B  = (size_t)BB * HH * 4;                 // 131,072
    const size_t XH_B = (size_t)65536 * IIP * 2;             // 41,943,040
    const size_t WH_B = (size_t)GG * IIP * 2;                // 655,360

    _Float16* xp = (_Float16*)d_ws;
    float* hf = (float*)((char*)d_ws + XP_B);
    float* hb = hf + (size_t)BB * HH;
    _Float16* Xh = (_Float16*)((char*)d_ws + XP_B + 2 * H_B);
    _Float16* Wh = Xh + (size_t)65536 * IIP;

    lstm_bwd<<<BB, 256, 0, stream>>>(x, Wihb, bbv, hb);
    if (ws_size >= XP_B + 2 * H_B + XH_B + WH_B) {
        cvt_xw<<<2048, 256, 0, stream>>>(x, Wihf, Xh, Wh);
        gemm_xp_h<<<dim3(GG / 128, (BB * TT) / 128), 256, 0, stream>>>(Xh, Wh, bf, xp);
    } else {
        gemm_xp<<<dim3(GG / 128, (BB * TT) / 128), 256, 0, stream>>>(x, Wihf, bf, xp);
    }
    lstm_fwd<<<BB, 512, 0, stream>>>(Whhf, xp, hf);
    final_k<<<1, 256, 0, stream>>>(hf, hb, Wlin, blin, out);
}